// Round 3
// baseline (258.122 us; speedup 1.0000x reference)
//
#include <hip/hip_runtime.h>

// Problem constants (match reference file)
constexpr int B = 32768;
constexpr int D = 1024;
constexpr int S = 64;
constexpr int O = 4;

constexpr int BLOCKS_PER_SID = 32;
constexpr int MAIN_BLOCKS    = S * BLOCKS_PER_SID;      // 2048 (= 8 blocks/CU, fully resident)
constexpr int WAVES_PER_SID  = BLOCKS_PER_SID * 4;      // 128 waves share one sid's rows

// ws layout (int32 offsets from base):
//   [0..63]    counts
//   [64..128]  offsets (exclusive scan, 65 entries)
//   [192..255] cursor (scatter write positions)
//   [256..]    perm[B] (row indices sorted by sid)
#define WS_COUNTS  0
#define WS_OFFSETS 64
#define WS_CURSOR  192
#define WS_PERM    256

__global__ __launch_bounds__(256) void hist_kernel(const int* __restrict__ sid,
                                                   int* __restrict__ ws) {
    __shared__ int h[S];
    if (threadIdx.x < S) h[threadIdx.x] = 0;
    __syncthreads();
    for (int i = blockIdx.x * blockDim.x + threadIdx.x; i < B; i += gridDim.x * blockDim.x)
        atomicAdd(&h[sid[i]], 1);
    __syncthreads();
    if (threadIdx.x < S) atomicAdd(&ws[WS_COUNTS + threadIdx.x], h[threadIdx.x]);
}

__global__ __launch_bounds__(64) void scan_kernel(int* __restrict__ ws) {
    if (threadIdx.x == 0) {
        int acc = 0;
        for (int s = 0; s < S; ++s) {
            ws[WS_OFFSETS + s] = acc;
            acc += ws[WS_COUNTS + s];
        }
        ws[WS_OFFSETS + S] = acc;
    }
    __syncthreads();
    // cursor starts at offsets
    ws[WS_CURSOR + threadIdx.x] = ws[WS_OFFSETS + threadIdx.x];
}

__global__ __launch_bounds__(256) void scatter_kernel(const int* __restrict__ sid,
                                                      int* __restrict__ ws) {
    for (int i = blockIdx.x * blockDim.x + threadIdx.x; i < B; i += gridDim.x * blockDim.x) {
        int pos = atomicAdd(&ws[WS_CURSOR + sid[i]], 1);
        ws[WS_PERM + pos] = i;
    }
}

// One block per (sid, chunk). Stage W[sid]^T into LDS once; stream rows.
__global__ __launch_bounds__(256) void main_kernel(const float* __restrict__ x,
                                                   const float* __restrict__ W,
                                                   const float* __restrict__ bias,
                                                   const int* __restrict__ ws,
                                                   float* __restrict__ out) {
    __shared__ float Wt[O][D];   // 16 KiB, transposed: Wt[o][d]

    const int s     = blockIdx.x / BLOCKS_PER_SID;
    const int chunk = blockIdx.x % BLOCKS_PER_SID;
    const int wave  = threadIdx.x >> 6;
    const int lane  = threadIdx.x & 63;

    // Cooperative stage: thread t loads W[s][d][0:4] float4 for d = t, t+256, ...
    const float* __restrict__ Wg = W + (size_t)s * (D * O);
    #pragma unroll
    for (int it = 0; it < D / 256; ++it) {
        const int d = it * 256 + threadIdx.x;
        const float4 wv = *(const float4*)(Wg + (size_t)d * O);
        Wt[0][d] = wv.x;
        Wt[1][d] = wv.y;
        Wt[2][d] = wv.z;
        Wt[3][d] = wv.w;
    }
    __syncthreads();

    const int start = ws[WS_OFFSETS + s];
    const int cnt   = ws[WS_OFFSETS + s + 1] - start;
    const int wv_id = chunk * 4 + wave;          // 0..127 within this sid

    const float4 bv = *(const float4*)(bias + s * O);

    int i = wv_id;
    int row = (i < cnt) ? ws[WS_PERM + start + i] : -1;
    while (i < cnt) {
        // prefetch next row index (hide perm L2 latency)
        const int i_next = i + WAVES_PER_SID;
        const int row_next = (i_next < cnt) ? ws[WS_PERM + start + i_next] : -1;

        const float* __restrict__ xr = x + (size_t)row * D;
        float a0 = 0.f, a1 = 0.f, a2 = 0.f, a3 = 0.f;
        #pragma unroll
        for (int k = 0; k < 4; ++k) {
            const int d0 = k * 256 + lane * 4;
            const float4 xv = *(const float4*)(xr + d0);
            const float4 w0 = *(const float4*)(&Wt[0][d0]);
            const float4 w1 = *(const float4*)(&Wt[1][d0]);
            const float4 w2 = *(const float4*)(&Wt[2][d0]);
            const float4 w3 = *(const float4*)(&Wt[3][d0]);
            a0 += xv.x * w0.x + xv.y * w0.y + xv.z * w0.z + xv.w * w0.w;
            a1 += xv.x * w1.x + xv.y * w1.y + xv.z * w1.z + xv.w * w1.w;
            a2 += xv.x * w2.x + xv.y * w2.y + xv.z * w2.z + xv.w * w2.w;
            a3 += xv.x * w3.x + xv.y * w3.y + xv.z * w3.z + xv.w * w3.w;
        }

        // Wave-64 butterfly reduction
        #pragma unroll
        for (int off = 32; off >= 1; off >>= 1) {
            a0 += __shfl_xor(a0, off, 64);
            a1 += __shfl_xor(a1, off, 64);
            a2 += __shfl_xor(a2, off, 64);
            a3 += __shfl_xor(a3, off, 64);
        }

        if (lane == 0) {
            float4 o4;
            o4.x = a0 + bv.x;
            o4.y = a1 + bv.y;
            o4.z = a2 + bv.z;
            o4.w = a3 + bv.w;
            *(float4*)(out + (size_t)row * O) = o4;
        }

        i = i_next;
        row = row_next;
    }
}

extern "C" void kernel_launch(void* const* d_in, const int* in_sizes, int n_in,
                              void* d_out, int out_size, void* d_ws, size_t ws_size,
                              hipStream_t stream) {
    const float* x    = (const float*)d_in[0];   // [B, D]
    const int*   sid  = (const int*)d_in[1];     // [B]
    const float* W    = (const float*)d_in[2];   // [S, D, O]
    const float* bias = (const float*)d_in[3];   // [S, O]
    float* out = (float*)d_out;                  // [B, O]
    int* ws = (int*)d_ws;

    // zero counts/offsets/cursor region (ws is re-poisoned to 0xAA each launch)
    hipMemsetAsync(ws, 0, WS_PERM * sizeof(int), stream);

    hist_kernel<<<64, 256, 0, stream>>>(sid, ws);
    scan_kernel<<<1, 64, 0, stream>>>(ws);
    scatter_kernel<<<128, 256, 0, stream>>>(sid, ws);
    main_kernel<<<MAIN_BLOCKS, 256, 0, stream>>>(x, W, bias, ws, out);
}

// Round 4
// 222.588 us; speedup vs baseline: 1.1596x; 1.1596x over previous
//
#include <hip/hip_runtime.h>

// Problem constants (match reference file)
constexpr int B = 32768;
constexpr int D = 1024;
constexpr int S = 64;
constexpr int O = 4;

constexpr int BLOCKS_PER_SID = 16;
constexpr int MAIN_BLOCKS    = S * BLOCKS_PER_SID;   // 1024 = 4 blocks/CU, fully co-resident
constexpr int WAVES_PER_SID  = BLOCKS_PER_SID * 4;   // 64 waves share one sid's rows

// ws layout (int32):
//   [0..64]   offsets (exclusive scan over sid counts, 65 entries)
//   [256..]   perm[B] (row indices grouped by sid)
#define WS_OFFSETS 0
#define WS_PERM    256

// Single-kernel counting sort: 1 block, 1024 threads. Each thread keeps its
// 32 (sid, rank) pairs in REGISTERS (rank via LDS atomicAdd — any order is a
// valid permutation), thread 0 does the 64-bin exclusive scan, then all
// threads scatter perm. No global atomics, no multi-kernel chain.
__global__ __launch_bounds__(1024) void sort_kernel(const int* __restrict__ sid,
                                                    int* __restrict__ ws) {
    __shared__ int h[S];
    __shared__ int off[S];
    const int t = threadIdx.x;
    if (t < S) h[t] = 0;
    __syncthreads();

    int myR[B / 1024];
    int myS[B / 1024];
    #pragma unroll
    for (int it = 0; it < B / 1024; ++it) {
        const int i = it * 1024 + t;
        const int s = sid[i];
        myS[it] = s;
        myR[it] = atomicAdd(&h[s], 1);   // LDS atomic: rank within sid
    }
    __syncthreads();

    if (t == 0) {
        int acc = 0;
        for (int s2 = 0; s2 < S; ++s2) {
            off[s2] = acc;
            ws[WS_OFFSETS + s2] = acc;
            acc += h[s2];
        }
        ws[WS_OFFSETS + S] = acc;
    }
    __syncthreads();

    #pragma unroll
    for (int it = 0; it < B / 1024; ++it) {
        const int i = it * 1024 + t;
        ws[WS_PERM + off[myS[it]] + myR[it]] = i;
    }
}

// One block per (sid, chunk). W[sid] is staged to LDS once (coalesced), then
// each lane pulls its fragment into 64 VGPRs: w[k][j] = W[s][k*256+lane*4+j][:].
// Per row: 4 coalesced dwordx4 x-loads + 64 FMAs + 18 shuffles. ZERO per-row
// LDS reads (R3's 8-way ds_read_b128 bank conflict is gone).
__global__ __launch_bounds__(256) void main_kernel(const float* __restrict__ x,
                                                   const float* __restrict__ W,
                                                   const float* __restrict__ bias,
                                                   const int* __restrict__ ws,
                                                   float* __restrict__ out) {
    __shared__ float4 Wl[D];   // 16 KiB: Wl[d] = W[s][d][0:4]

    const int s    = blockIdx.x / BLOCKS_PER_SID;
    const int blk  = blockIdx.x % BLOCKS_PER_SID;
    const int wave = threadIdx.x >> 6;
    const int lane = threadIdx.x & 63;

    const float4* __restrict__ Wg = (const float4*)(W + (size_t)s * (D * O));
    for (int d = threadIdx.x; d < D; d += 256) Wl[d] = Wg[d];
    __syncthreads();

    float4 w[4][4];
    #pragma unroll
    for (int k = 0; k < 4; ++k)
        #pragma unroll
        for (int j = 0; j < 4; ++j)
            w[k][j] = Wl[k * 256 + lane * 4 + j];   // one-time; conflicts amortized

    const int start = ws[WS_OFFSETS + s];
    const int cnt   = ws[WS_OFFSETS + s + 1] - start;
    const int wv_id = blk * 4 + wave;

    const int   q  = (lane >> 2) & 3;         // output index this lane owns at the end
    const float bb = bias[s * O + q];

    int i   = wv_id;
    int row = (i < cnt) ? ws[WS_PERM + start + i] : 0;
    while (i < cnt) {
        const int i_next   = i + WAVES_PER_SID;
        const int row_next = (i_next < cnt) ? ws[WS_PERM + start + i_next] : 0;

        const float* __restrict__ xr = x + (size_t)row * D;
        float a0 = 0.f, a1 = 0.f, a2 = 0.f, a3 = 0.f;
        #pragma unroll
        for (int k = 0; k < 4; ++k) {
            const float4 xv = *(const float4*)(xr + k * 256 + lane * 4);
            a0 += xv.x * w[k][0].x + xv.y * w[k][1].x + xv.z * w[k][2].x + xv.w * w[k][3].x;
            a1 += xv.x * w[k][0].y + xv.y * w[k][1].y + xv.z * w[k][2].y + xv.w * w[k][3].y;
            a2 += xv.x * w[k][0].z + xv.y * w[k][1].z + xv.z * w[k][2].z + xv.w * w[k][3].z;
            a3 += xv.x * w[k][0].w + xv.y * w[k][1].w + xv.z * w[k][2].w + xv.w * w[k][3].w;
        }

        // Reduction, 18 DS ops:
        // xor{4,8,16,32}: lane l holds S_o[l&3] (partial over residue class l&3)
        #pragma unroll
        for (int m = 4; m <= 32; m <<= 1) {
            a0 += __shfl_xor(a0, m, 64);
            a1 += __shfl_xor(a1, m, 64);
            a2 += __shfl_xor(a2, m, 64);
            a3 += __shfl_xor(a3, m, 64);
        }
        // lane l takes output q=(l>>2)&3; xor{1,2} sums the 4 residue classes
        // (lanes l, l^1, l^2, l^3 share the same q).
        float v = (q == 0) ? a0 : (q == 1) ? a1 : (q == 2) ? a2 : a3;
        v += __shfl_xor(v, 1, 64);
        v += __shfl_xor(v, 2, 64);

        if (lane < 16 && (lane & 3) == 0)     // lanes 0,4,8,12 -> o = 0,1,2,3
            out[(size_t)row * O + q] = v + bb;

        i   = i_next;
        row = row_next;
    }
}

extern "C" void kernel_launch(void* const* d_in, const int* in_sizes, int n_in,
                              void* d_out, int out_size, void* d_ws, size_t ws_size,
                              hipStream_t stream) {
    const float* x    = (const float*)d_in[0];   // [B, D]
    const int*   sid  = (const int*)d_in[1];     // [B]
    const float* W    = (const float*)d_in[2];   // [S, D, O]
    const float* bias = (const float*)d_in[3];   // [S, O]
    float* out = (float*)d_out;                  // [B, O]
    int* ws = (int*)d_ws;

    sort_kernel<<<1, 1024, 0, stream>>>(sid, ws);
    main_kernel<<<MAIN_BLOCKS, 256, 0, stream>>>(x, W, bias, ws, out);
}

// Round 5
// 205.889 us; speedup vs baseline: 1.2537x; 1.0811x over previous
//
#include <hip/hip_runtime.h>

// Problem constants (match reference file)
constexpr int B = 32768;
constexpr int D = 1024;
constexpr int S = 64;
constexpr int O = 4;

constexpr int BLOCKS_PER_SID = 16;
constexpr int MAIN_BLOCKS    = S * BLOCKS_PER_SID;   // 1024 = 4 blocks/CU
constexpr int WAVES_PER_SID  = BLOCKS_PER_SID * 4;   // 64 waves share one sid's rows

constexpr int SORT_BLOCKS   = 64;
constexpr int ROWS_PER_SBLK = B / SORT_BLOCKS;       // 512

// ws layout (int32):
//   [0..64]       offsets (exclusive scan over sid counts, 65 entries)
//   [128..4224)   base[b][s]: scatter base for sort-block b, sid s (64x64)
//   [8192..12288) hist[b][s]
//   [16384..)     perm[B]
#define WS_OFFSETS 0
#define WS_BASE    128
#define WS_HIST    8192
#define WS_PERM    16384

// A: per-block histogram (64 blocks, each 512 rows). LDS atomics only.
__global__ __launch_bounds__(256) void hist_kernel(const int* __restrict__ sid,
                                                   int* __restrict__ ws) {
    __shared__ int h[S];
    const int t = threadIdx.x, b = blockIdx.x;
    if (t < S) h[t] = 0;
    __syncthreads();
    const int rbase = b * ROWS_PER_SBLK;
    atomicAdd(&h[sid[rbase + t]], 1);
    atomicAdd(&h[sid[rbase + 256 + t]], 1);
    __syncthreads();
    if (t < S) ws[WS_HIST + b * S + t] = h[t];
}

// B: 64 threads; thread s scans hist[:,s] down the blocks, then thread 0
// scans bin totals; emit base[b][s] = off[s] + sum_{b'<b} hist[b'][s].
__global__ __launch_bounds__(64) void scan_kernel(int* __restrict__ ws) {
    __shared__ int tot[S];
    __shared__ int off[S + 1];
    const int s = threadIdx.x;
    int basev[SORT_BLOCKS];
    int acc = 0;
    #pragma unroll
    for (int b = 0; b < SORT_BLOCKS; ++b) {
        basev[b] = acc;
        acc += ws[WS_HIST + b * S + s];   // coalesced across threads per b
    }
    tot[s] = acc;
    __syncthreads();
    if (s == 0) {
        int a = 0;
        for (int i = 0; i < S; ++i) { off[i] = a; a += tot[i]; }
        off[S] = a;
    }
    __syncthreads();
    const int o = off[s];
    ws[WS_OFFSETS + s] = o;
    if (s == 0) ws[WS_OFFSETS + S] = off[S];
    #pragma unroll
    for (int b = 0; b < SORT_BLOCKS; ++b)
        ws[WS_BASE + b * S + s] = basev[b] + o;
}

// C: block b re-ranks its 512 rows (LDS atomics, any order is a valid
// permutation) and scatters perm using its private bases. No global atomics.
__global__ __launch_bounds__(256) void scatter_kernel(const int* __restrict__ sid,
                                                      int* __restrict__ ws) {
    __shared__ int cur[S];
    __shared__ int bas[S];
    const int t = threadIdx.x, b = blockIdx.x;
    if (t < S) { cur[t] = 0; bas[t] = ws[WS_BASE + b * S + t]; }
    __syncthreads();
    const int rbase = b * ROWS_PER_SBLK;
    const int i0 = rbase + t, i1 = rbase + 256 + t;
    const int s0 = sid[i0], s1 = sid[i1];
    const int r0 = atomicAdd(&cur[s0], 1);
    const int r1 = atomicAdd(&cur[s1], 1);
    ws[WS_PERM + bas[s0] + r0] = i0;
    ws[WS_PERM + bas[s1] + r1] = i1;
}

// Main: one block per (sid, chunk). W[sid] staged to LDS once (coalesced),
// then each lane holds its fragment in 64 VGPRs. Per row: 4 coalesced
// dwordx4 x-loads + 64 FMAs + 18 shuffles. Zero per-row LDS reads.
__global__ __launch_bounds__(256) void main_kernel(const float* __restrict__ x,
                                                   const float* __restrict__ W,
                                                   const float* __restrict__ bias,
                                                   const int* __restrict__ ws,
                                                   float* __restrict__ out) {
    __shared__ float4 Wl[D];   // 16 KiB

    const int s    = blockIdx.x / BLOCKS_PER_SID;
    const int blk  = blockIdx.x % BLOCKS_PER_SID;
    const int wave = threadIdx.x >> 6;
    const int lane = threadIdx.x & 63;

    const float4* __restrict__ Wg = (const float4*)(W + (size_t)s * (D * O));
    for (int d = threadIdx.x; d < D; d += 256) Wl[d] = Wg[d];
    __syncthreads();

    float4 w[4][4];
    #pragma unroll
    for (int k = 0; k < 4; ++k)
        #pragma unroll
        for (int j = 0; j < 4; ++j)
            w[k][j] = Wl[k * 256 + lane * 4 + j];   // one-time; conflicts amortized

    const int start = ws[WS_OFFSETS + s];
    const int cnt   = ws[WS_OFFSETS + s + 1] - start;
    const int wv_id = blk * 4 + wave;

    const int   q  = (lane >> 2) & 3;   // output index this lane owns at the end
    const float bb = bias[s * O + q];

    int i   = wv_id;
    int row = (i < cnt) ? ws[WS_PERM + start + i] : 0;
    while (i < cnt) {
        const int i_next   = i + WAVES_PER_SID;
        const int row_next = (i_next < cnt) ? ws[WS_PERM + start + i_next] : 0;

        const float* __restrict__ xr = x + (size_t)row * D;
        float a0 = 0.f, a1 = 0.f, a2 = 0.f, a3 = 0.f;
        #pragma unroll
        for (int k = 0; k < 4; ++k) {
            const float4 xv = *(const float4*)(xr + k * 256 + lane * 4);
            a0 += xv.x * w[k][0].x + xv.y * w[k][1].x + xv.z * w[k][2].x + xv.w * w[k][3].x;
            a1 += xv.x * w[k][0].y + xv.y * w[k][1].y + xv.z * w[k][2].y + xv.w * w[k][3].y;
            a2 += xv.x * w[k][0].z + xv.y * w[k][1].z + xv.z * w[k][2].z + xv.w * w[k][3].z;
            a3 += xv.x * w[k][0].w + xv.y * w[k][1].w + xv.z * w[k][2].w + xv.w * w[k][3].w;
        }

        // xor{4,8,16,32}: lane l holds S_o[l&3]; then lane picks q=(l>>2)&3,
        // xor{1,2} sums the 4 residue classes; lanes 0,4,8,12 write o=0..3.
        #pragma unroll
        for (int m = 4; m <= 32; m <<= 1) {
            a0 += __shfl_xor(a0, m, 64);
            a1 += __shfl_xor(a1, m, 64);
            a2 += __shfl_xor(a2, m, 64);
            a3 += __shfl_xor(a3, m, 64);
        }
        float v = (q == 0) ? a0 : (q == 1) ? a1 : (q == 2) ? a2 : a3;
        v += __shfl_xor(v, 1, 64);
        v += __shfl_xor(v, 2, 64);

        if (lane < 16 && (lane & 3) == 0)
            out[(size_t)row * O + q] = v + bb;

        i   = i_next;
        row = row_next;
    }
}

extern "C" void kernel_launch(void* const* d_in, const int* in_sizes, int n_in,
                              void* d_out, int out_size, void* d_ws, size_t ws_size,
                              hipStream_t stream) {
    const float* x    = (const float*)d_in[0];   // [B, D]
    const int*   sid  = (const int*)d_in[1];     // [B]
    const float* W    = (const float*)d_in[2];   // [S, D, O]
    const float* bias = (const float*)d_in[3];   // [S, O]
    float* out = (float*)d_out;                  // [B, O]
    int* ws = (int*)d_ws;

    hist_kernel   <<<SORT_BLOCKS, 256, 0, stream>>>(sid, ws);
    scan_kernel   <<<1,            64, 0, stream>>>(ws);
    scatter_kernel<<<SORT_BLOCKS, 256, 0, stream>>>(sid, ws);
    main_kernel   <<<MAIN_BLOCKS, 256, 0, stream>>>(x, W, bias, ws, out);
}

// Round 6
// 204.405 us; speedup vs baseline: 1.2628x; 1.0073x over previous
//
#include <hip/hip_runtime.h>

// Problem constants (match reference file)
constexpr int B = 32768;
constexpr int D = 1024;
constexpr int S = 64;
constexpr int O = 4;

constexpr int BLOCKS_PER_SID = 16;
constexpr int MAIN_BLOCKS    = S * BLOCKS_PER_SID;   // 1024 = 4 blocks/CU
constexpr int WAVES_PER_SID  = BLOCKS_PER_SID * 4;   // 64 waves share one sid's rows

constexpr int SORT_BLOCKS   = 64;
constexpr int ROWS_PER_SBLK = B / SORT_BLOCKS;       // 512

// ws layout (int32):
//   [0..64]       offsets (exclusive scan over sid counts, 65 entries)
//   [128..4224)   base[b][s]: scatter base for sort-block b, sid s (64x64)
//   [8192..12288) hist[b][s]
//   [16384..)     perm[B]
#define WS_OFFSETS 0
#define WS_BASE    128
#define WS_HIST    8192
#define WS_PERM    16384

// LDS bank swizzle for float4 W tile: e -> e ^ ((e>>3)&7).
// Pickup reads (e = k*256 + 4*lane + j) become conflict-free per 8-lane batch;
// staging writes (e = t + 256*it) stay conflict-free.
__device__ __forceinline__ int swz(int e) { return e ^ ((e >> 3) & 7); }

// A: per-block histogram (64 blocks, each 512 rows). LDS atomics only.
__global__ __launch_bounds__(256) void hist_kernel(const int* __restrict__ sid,
                                                   int* __restrict__ ws) {
    __shared__ int h[S];
    const int t = threadIdx.x, b = blockIdx.x;
    if (t < S) h[t] = 0;
    __syncthreads();
    const int rbase = b * ROWS_PER_SBLK;
    atomicAdd(&h[sid[rbase + t]], 1);
    atomicAdd(&h[sid[rbase + 256 + t]], 1);
    __syncthreads();
    if (t < S) ws[WS_HIST + b * S + t] = h[t];
}

// B: 64 threads; thread s scans hist[:,s] down the blocks, thread 0 scans
// bin totals; emit base[b][s] = off[s] + sum_{b'<b} hist[b'][s].
__global__ __launch_bounds__(64) void scan_kernel(int* __restrict__ ws) {
    __shared__ int tot[S];
    __shared__ int off[S + 1];
    const int s = threadIdx.x;
    int basev[SORT_BLOCKS];
    int acc = 0;
    #pragma unroll
    for (int b = 0; b < SORT_BLOCKS; ++b) {
        basev[b] = acc;
        acc += ws[WS_HIST + b * S + s];
    }
    tot[s] = acc;
    __syncthreads();
    if (s == 0) {
        int a = 0;
        for (int i = 0; i < S; ++i) { off[i] = a; a += tot[i]; }
        off[S] = a;
    }
    __syncthreads();
    const int o = off[s];
    ws[WS_OFFSETS + s] = o;
    if (s == 0) ws[WS_OFFSETS + S] = off[S];
    #pragma unroll
    for (int b = 0; b < SORT_BLOCKS; ++b)
        ws[WS_BASE + b * S + s] = basev[b] + o;
}

// C: block b re-ranks its 512 rows (LDS atomics) and scatters perm using its
// private bases. No global atomics.
__global__ __launch_bounds__(256) void scatter_kernel(const int* __restrict__ sid,
                                                      int* __restrict__ ws) {
    __shared__ int cur[S];
    __shared__ int bas[S];
    const int t = threadIdx.x, b = blockIdx.x;
    if (t < S) { cur[t] = 0; bas[t] = ws[WS_BASE + b * S + t]; }
    __syncthreads();
    const int rbase = b * ROWS_PER_SBLK;
    const int i0 = rbase + t, i1 = rbase + 256 + t;
    const int s0 = sid[i0], s1 = sid[i1];
    const int r0 = atomicAdd(&cur[s0], 1);
    const int r1 = atomicAdd(&cur[s1], 1);
    ws[WS_PERM + bas[s0] + r0] = i0;
    ws[WS_PERM + bas[s1] + r1] = i1;
}

// Main: one block per (sid, chunk). W[sid] staged to LDS once (swizzled),
// fragments pulled into 64 VGPRs conflict-free. Per row: 4 coalesced
// dwordx4 x-loads (prefetched one row ahead) + 64 FMAs + 12 shuffles.
__global__ __launch_bounds__(256, 4) void main_kernel(const float* __restrict__ x,
                                                      const float* __restrict__ W,
                                                      const float* __restrict__ bias,
                                                      const int* __restrict__ ws,
                                                      float* __restrict__ out) {
    __shared__ float4 Wl[D];   // 16 KiB, XOR-swizzled

    const int s    = blockIdx.x / BLOCKS_PER_SID;
    const int blk  = blockIdx.x % BLOCKS_PER_SID;
    const int wave = threadIdx.x >> 6;
    const int lane = threadIdx.x & 63;

    const float4* __restrict__ Wg = (const float4*)(W + (size_t)s * (D * O));
    for (int e = threadIdx.x; e < D; e += 256) Wl[swz(e)] = Wg[e];
    __syncthreads();

    float4 w[4][4];
    #pragma unroll
    for (int k = 0; k < 4; ++k)
        #pragma unroll
        for (int j = 0; j < 4; ++j)
            w[k][j] = Wl[swz(k * 256 + lane * 4 + j)];

    const int start = ws[WS_OFFSETS + s];
    const int cnt   = ws[WS_OFFSETS + s + 1] - start;
    const int wv_id = blk * 4 + wave;

    const int   q  = lane >> 4;          // output index this lane owns at the end
    const float bb = bias[s * O + q];

    int i   = wv_id;
    int row = (i < cnt) ? ws[WS_PERM + start + i] : 0;

    float4 xv0, xv1, xv2, xv3;
    if (i < cnt) {
        const float* __restrict__ xr = x + (size_t)row * D;
        xv0 = *(const float4*)(xr + 0 * 256 + lane * 4);
        xv1 = *(const float4*)(xr + 1 * 256 + lane * 4);
        xv2 = *(const float4*)(xr + 2 * 256 + lane * 4);
        xv3 = *(const float4*)(xr + 3 * 256 + lane * 4);
    }

    while (i < cnt) {
        const int i_next   = i + WAVES_PER_SID;
        const int row_next = (i_next < cnt) ? ws[WS_PERM + start + i_next] : 0;

        float a0, a1, a2, a3;
        {
            a0  = xv0.x * w[0][0].x + xv0.y * w[0][1].x + xv0.z * w[0][2].x + xv0.w * w[0][3].x;
            a1  = xv0.x * w[0][0].y + xv0.y * w[0][1].y + xv0.z * w[0][2].y + xv0.w * w[0][3].y;
            a2  = xv0.x * w[0][0].z + xv0.y * w[0][1].z + xv0.z * w[0][2].z + xv0.w * w[0][3].z;
            a3  = xv0.x * w[0][0].w + xv0.y * w[0][1].w + xv0.z * w[0][2].w + xv0.w * w[0][3].w;
            a0 += xv1.x * w[1][0].x + xv1.y * w[1][1].x + xv1.z * w[1][2].x + xv1.w * w[1][3].x;
            a1 += xv1.x * w[1][0].y + xv1.y * w[1][1].y + xv1.z * w[1][2].y + xv1.w * w[1][3].y;
            a2 += xv1.x * w[1][0].z + xv1.y * w[1][1].z + xv1.z * w[1][2].z + xv1.w * w[1][3].z;
            a3 += xv1.x * w[1][0].w + xv1.y * w[1][1].w + xv1.z * w[1][2].w + xv1.w * w[1][3].w;
            a0 += xv2.x * w[2][0].x + xv2.y * w[2][1].x + xv2.z * w[2][2].x + xv2.w * w[2][3].x;
            a1 += xv2.x * w[2][0].y + xv2.y * w[2][1].y + xv2.z * w[2][2].y + xv2.w * w[2][3].y;
            a2 += xv2.x * w[2][0].z + xv2.y * w[2][1].z + xv2.z * w[2][2].z + xv2.w * w[2][3].z;
            a3 += xv2.x * w[2][0].w + xv2.y * w[2][1].w + xv2.z * w[2][2].w + xv2.w * w[2][3].w;
            a0 += xv3.x * w[3][0].x + xv3.y * w[3][1].x + xv3.z * w[3][2].x + xv3.w * w[3][3].x;
            a1 += xv3.x * w[3][0].y + xv3.y * w[3][1].y + xv3.z * w[3][2].y + xv3.w * w[3][3].y;
            a2 += xv3.x * w[3][0].z + xv3.y * w[3][1].z + xv3.z * w[3][2].z + xv3.w * w[3][3].z;
            a3 += xv3.x * w[3][0].w + xv3.y * w[3][1].w + xv3.z * w[3][2].w + xv3.w * w[3][3].w;
        }

        // Prefetch next row's x while the reduction chain runs.
        if (i_next < cnt) {
            const float* __restrict__ xn = x + (size_t)row_next * D;
            xv0 = *(const float4*)(xn + 0 * 256 + lane * 4);
            xv1 = *(const float4*)(xn + 1 * 256 + lane * 4);
            xv2 = *(const float4*)(xn + 2 * 256 + lane * 4);
            xv3 = *(const float4*)(xn + 3 * 256 + lane * 4);
        }

        // 12-op reduction: xor{16,32} on 4 accs -> per-(lane%16) partials;
        // lane picks q = lane>>4; xor{1,2,4,8} sums the 16 residues.
        #pragma unroll
        for (int m = 16; m <= 32; m <<= 1) {
            a0 += __shfl_xor(a0, m, 64);
            a1 += __shfl_xor(a1, m, 64);
            a2 += __shfl_xor(a2, m, 64);
            a3 += __shfl_xor(a3, m, 64);
        }
        float v = (q == 0) ? a0 : (q == 1) ? a1 : (q == 2) ? a2 : a3;
        #pragma unroll
        for (int m = 1; m <= 8; m <<= 1)
            v += __shfl_xor(v, m, 64);

        if ((lane & 15) == 0)                 // lanes 0,16,32,48 -> o = 0..3
            out[(size_t)row * O + q] = v + bb;

        i   = i_next;
        row = row_next;
    }
}

extern "C" void kernel_launch(void* const* d_in, const int* in_sizes, int n_in,
                              void* d_out, int out_size, void* d_ws, size_t ws_size,
                              hipStream_t stream) {
    const float* x    = (const float*)d_in[0];   // [B, D]
    const int*   sid  = (const int*)d_in[1];     // [B]
    const float* W    = (const float*)d_in[2];   // [S, D, O]
    const float* bias = (const float*)d_in[3];   // [S, O]
    float* out = (float*)d_out;                  // [B, O]
    int* ws = (int*)d_ws;

    hist_kernel   <<<SORT_BLOCKS, 256, 0, stream>>>(sid, ws);
    scan_kernel   <<<1,            64, 0, stream>>>(ws);
    scatter_kernel<<<SORT_BLOCKS, 256, 0, stream>>>(sid, ws);
    main_kernel   <<<MAIN_BLOCKS, 256, 0, stream>>>(x, W, bias, ws, out);
}